// Round 6
// baseline (212.523 us; speedup 1.0000x reference)
//
#include <hip/hip_runtime.h>
#include <hip/hip_bf16.h>

typedef float f4 __attribute__((ext_vector_type(4)));

constexpr int B   = 16;
constexpr int P   = 87;
constexpr int K   = 4;
constexpr int N   = 32768;
constexpr int D   = 256;
constexpr int HID = 128;
constexpr int CH  = 128;         // chunks per batch
constexpr int CHN = N / CH;      // 256 rows per chunk
constexpr float SCL = 0.125f;    // ATTN_SCALE / TAU

constexpr int AB  = B * CH;      // 2048 attention blocks (first in grid)
constexpr int HB  = (B * P) / 4; // 348 human-head blocks (after attn)

__device__ __forceinline__ f4 ntload(const float* p) {
    return __builtin_nontemporal_load((const f4*)p);
}

// ---------------------------------------------------------------------------
// q = object_queries @ Wq + bq   (computed once; 64 blocks).
// Also zeroes the per-batch completion counters used by fused_main.
// ---------------------------------------------------------------------------
__global__ __launch_bounds__(256) void qproj(const float* __restrict__ oq,
                                             const float* __restrict__ Wq,
                                             const float* __restrict__ bq,
                                             float* __restrict__ q,
                                             unsigned* __restrict__ counter) {
    if (blockIdx.x == 0 && threadIdx.x < B) counter[threadIdx.x] = 0u;

    const int row = blockIdx.x;       // 0..B*K-1
    const int j   = threadIdx.x;      // 0..D-1
    const float* x = oq + (size_t)row * D;
    float a0 = bq[j], a1 = 0.f, a2 = 0.f, a3 = 0.f;
#pragma unroll 8
    for (int i = 0; i < D; i += 4) {
        a0 = fmaf(x[i + 0], Wq[(size_t)(i + 0) * D + j], a0);
        a1 = fmaf(x[i + 1], Wq[(size_t)(i + 1) * D + j], a1);
        a2 = fmaf(x[i + 2], Wq[(size_t)(i + 2) * D + j], a2);
        a3 = fmaf(x[i + 3], Wq[(size_t)(i + 3) * D + j], a3);
    }
    q[(size_t)row * D + j] = (a0 + a1) + (a2 + a3);
}

// ---------------------------------------------------------------------------
// Fused kernel: blocks [0, AB) = attention (+ last-block-per-batch coordinate
// finalize), blocks [AB, AB+HB) = human head.
// ---------------------------------------------------------------------------
__global__ __launch_bounds__(256) void fused_main(const float* __restrict__ feats,
                                                  const float* __restrict__ xyz,
                                                  const float* __restrict__ q,
                                                  const float* __restrict__ hq,
                                                  const float* __restrict__ W1,
                                                  const float* __restrict__ b1,
                                                  const float* __restrict__ W2,
                                                  const float* __restrict__ b2,
                                                  float* __restrict__ part,
                                                  unsigned* __restrict__ counter,
                                                  float* __restrict__ out) {
    __shared__ float sxyz[CHN * 3];            // 3 KB
    __shared__ float red[4][K * 4];
    __shared__ float sred[2][2][2];
    __shared__ unsigned scnt;

    const int bid = blockIdx.x;
    const int tid = threadIdx.x;

    if (bid >= AB) {
        // ---------------- human contact head: 4 rows per block --------------
        const int hbid = bid - AB;
        const int j    = tid & (HID - 1);
        const int rp   = tid >> 7;
        const int row0 = hbid * 4 + rp * 2;

        const float* x0 = hq + (size_t)row0 * D;
        const float* x1 = x0 + D;
        float acc0 = b1[j];
        float acc1 = acc0;
#pragma unroll 4
        for (int i = 0; i < D; ++i) {
            const float wv = W1[(size_t)i * HID + j];
            acc0 = fmaf(x0[i], wv, acc0);
            acc1 = fmaf(x1[i], wv, acc1);
        }
        const float w2 = W2[j];
        float v0 = fmaxf(acc0, 0.f) * w2;
        float v1 = fmaxf(acc1, 0.f) * w2;
#pragma unroll
        for (int off = 32; off; off >>= 1) {
            v0 += __shfl_xor(v0, off);
            v1 += __shfl_xor(v1, off);
        }
        const int lane = tid & 63;
        const int wh   = (tid >> 6) & 1;
        if (lane == 0) { sred[rp][wh][0] = v0; sred[rp][wh][1] = v1; }
        __syncthreads();
        if (tid < 2) {
            const float bb = b2[0];
            const float l0 = sred[tid][0][0] + sred[tid][1][0] + bb;
            const float l1 = sred[tid][0][1] + sred[tid][1][1] + bb;
            const int r = hbid * 4 + tid * 2;
            out[B * P + r + 0] = l0;
            out[B * P + r + 1] = l1;
            out[r + 0] = 1.f / (1.f + __expf(-l0));
            out[r + 1] = 1.f / (1.f + __expf(-l1));
        }
        return;
    }

    // ------------------------ attention pooling -----------------------------
    const int b    = bid >> 7;                 // batch
    const int ch   = bid & (CH - 1);           // chunk
    const int lane = tid & 63;
    const int w    = tid >> 6;                 // wave 0..3
    const int sg   = lane >> 4;                // subgroup (row slot) 0..3
    const int m    = lane & 15;                // 16-lane index

    const float* fbase = feats + ((size_t)b * N + (size_t)ch * CHN) * D;
    constexpr int NG = CHN / 4;                // 64 row-groups per chunk

    // first prefetch group issued immediately
    f4 f0, f1, f2, f3;
    {
        const float* rp = fbase + (size_t)(w * 4 + sg) * D + m * 4;
        f0 = ntload(rp + 0);
        f1 = ntload(rp + 64);
        f2 = ntload(rp + 128);
        f3 = ntload(rp + 192);
    }

    // stage this chunk's xyz into LDS (coalesced)
    const float* xsrc = xyz + ((size_t)b * N + (size_t)ch * CHN) * 3;
    for (int i = tid; i < CHN * 3; i += 256) sxyz[i] = xsrc[i];

    // q fragments: lane m holds cols {j*64 + 4m .. +4} for j=0..3, per k
    f4 qv[K][4];
#pragma unroll
    for (int k = 0; k < K; ++k)
#pragma unroll
        for (int j = 0; j < 4; ++j)
            qv[k][j] = *(const f4*)(q + (size_t)(b * K + k) * D + j * 64 + m * 4);

    __syncthreads();

    float s_[K] = {0.f, 0.f, 0.f, 0.f};
    float ax[K] = {0.f, 0.f, 0.f, 0.f};
    float ay[K] = {0.f, 0.f, 0.f, 0.f};
    float az[K] = {0.f, 0.f, 0.f, 0.f};

    for (int g = w; g < NG; g += 4) {
        const f4 c0 = f0, c1 = f1, c2 = f2, c3 = f3;
        const int gn = g + 4;
        if (gn < NG) {                          // prefetch next group
            const float* rp = fbase + (size_t)(gn * 4 + sg) * D + m * 4;
            f0 = ntload(rp + 0);
            f1 = ntload(rp + 64);
            f2 = ntload(rp + 128);
            f3 = ntload(rp + 192);
        }
        const int r = g * 4 + sg;

        float d[K];
#pragma unroll
        for (int k = 0; k < K; ++k) {
            float t0 = c0.x * qv[k][0].x;
            t0 = fmaf(c0.y, qv[k][0].y, t0);
            t0 = fmaf(c0.z, qv[k][0].z, t0);
            t0 = fmaf(c0.w, qv[k][0].w, t0);
            float t1 = c1.x * qv[k][1].x;
            t1 = fmaf(c1.y, qv[k][1].y, t1);
            t1 = fmaf(c1.z, qv[k][1].z, t1);
            t1 = fmaf(c1.w, qv[k][1].w, t1);
            t0 = fmaf(c2.x, qv[k][2].x, t0);
            t0 = fmaf(c2.y, qv[k][2].y, t0);
            t0 = fmaf(c2.z, qv[k][2].z, t0);
            t0 = fmaf(c2.w, qv[k][2].w, t0);
            t1 = fmaf(c3.x, qv[k][3].x, t1);
            t1 = fmaf(c3.y, qv[k][3].y, t1);
            t1 = fmaf(c3.z, qv[k][3].z, t1);
            t1 = fmaf(c3.w, qv[k][3].w, t1);
            d[k] = t0 + t1;
        }
#pragma unroll
        for (int k = 0; k < K; ++k) {
            float v = d[k];
            v += __shfl_xor(v, 8);
            v += __shfl_xor(v, 4);
            v += __shfl_xor(v, 2);
            v += __shfl_xor(v, 1);
            d[k] = v;
        }

        const float x = sxyz[r * 3 + 0];
        const float y = sxyz[r * 3 + 1];
        const float z = sxyz[r * 3 + 2];
#pragma unroll
        for (int k = 0; k < K; ++k) {
            const float e = __expf(d[k] * SCL);
            s_[k] += e;
            ax[k] = fmaf(e, x, ax[k]);
            ay[k] = fmaf(e, y, ay[k]);
            az[k] = fmaf(e, z, az[k]);
        }
    }

    // combine the 4 subgroups, then the 4 waves via LDS
#pragma unroll
    for (int k = 0; k < K; ++k) {
        float v;
        v = s_[k]; v += __shfl_xor(v, 16); v += __shfl_xor(v, 32); s_[k] = v;
        v = ax[k]; v += __shfl_xor(v, 16); v += __shfl_xor(v, 32); ax[k] = v;
        v = ay[k]; v += __shfl_xor(v, 16); v += __shfl_xor(v, 32); ay[k] = v;
        v = az[k]; v += __shfl_xor(v, 16); v += __shfl_xor(v, 32); az[k] = v;
    }
    if (lane == 0) {
#pragma unroll
        for (int k = 0; k < K; ++k) {
            red[w][k * 4 + 0] = s_[k];
            red[w][k * 4 + 1] = ax[k];
            red[w][k * 4 + 2] = ay[k];
            red[w][k * 4 + 3] = az[k];
        }
    }
    __syncthreads();
    if (tid < K * 4) {
        const float v = red[0][tid] + red[1][tid] + red[2][tid] + red[3][tid];
        part[((size_t)b * CH + ch) * (K * 4) + tid] = v;
    }
    __syncthreads();

    // publish this block's partial; last block of batch b finalizes coords.
    if (tid == 0) {
        __threadfence();                       // release part[] write
        scnt = atomicAdd(&counter[b], 1u);
    }
    __syncthreads();
    if (scnt == CH - 1) {                      // block-uniform branch
        __threadfence();                       // acquire other blocks' part[]
        const float* pb = part + (size_t)b * CH * (K * 4) + w * 4;
        f4 v = *(const f4*)(pb + (size_t)lane * (K * 4));
        f4 u = *(const f4*)(pb + (size_t)(lane + 64) * (K * 4));
        v.x += u.x; v.y += u.y; v.z += u.z; v.w += u.w;
#pragma unroll
        for (int off = 32; off; off >>= 1) {
            v.x += __shfl_xor(v.x, off);
            v.y += __shfl_xor(v.y, off);
            v.z += __shfl_xor(v.z, off);
            v.w += __shfl_xor(v.w, off);
        }
        if (lane == 0) {
            const float inv = 1.f / v.x;
            float* o = out + 2 * B * P + (b * K + w) * 3;
            o[0] = v.y * inv;
            o[1] = v.z * inv;
            o[2] = v.w * inv;
        }
    }
}

// ---------------------------------------------------------------------------
extern "C" void kernel_launch(void* const* d_in, const int* in_sizes, int n_in,
                              void* d_out, int out_size, void* d_ws, size_t ws_size,
                              hipStream_t stream) {
    const float* hq    = (const float*)d_in[0];
    const float* oq    = (const float*)d_in[1];
    const float* feats = (const float*)d_in[2];
    const float* xyz   = (const float*)d_in[3];
    const float* W1    = (const float*)d_in[4];
    const float* b1    = (const float*)d_in[5];
    const float* W2    = (const float*)d_in[6];
    const float* b2    = (const float*)d_in[7];
    const float* Wq    = (const float*)d_in[8];
    const float* bq    = (const float*)d_in[9];
    float* out = (float*)d_out;

    float*    q       = (float*)d_ws;                 // B*K*D floats
    float*    part    = q + (size_t)B * K * D;        // B*CH*K*4 floats
    unsigned* counter = (unsigned*)(part + (size_t)B * CH * K * 4);  // B uints

    qproj<<<B * K, 256, 0, stream>>>(oq, Wq, bq, q, counter);
    fused_main<<<AB + HB, 256, 0, stream>>>(feats, xyz, q, hq, W1, b1, W2, b2,
                                            part, counter, out);
}

// Round 7
// 103.188 us; speedup vs baseline: 2.0596x; 2.0596x over previous
//
#include <hip/hip_runtime.h>
#include <hip/hip_bf16.h>

typedef float f4 __attribute__((ext_vector_type(4)));

constexpr int B   = 16;
constexpr int P   = 87;
constexpr int K   = 4;
constexpr int N   = 32768;
constexpr int D   = 256;
constexpr int HID = 128;
constexpr int CH  = 256;         // chunks per batch
constexpr int CHN = N / CH;      // 128 rows per chunk
constexpr float SCL = 0.125f;    // ATTN_SCALE / TAU

constexpr int AB  = B * CH;      // 4096 attention blocks (first in grid)
constexpr int HB  = (B * P) / 4; // 348 human-head blocks (after attn)

__device__ __forceinline__ f4 ntload(const float* p) {
    return __builtin_nontemporal_load((const f4*)p);
}

// ---------------------------------------------------------------------------
// q = object_queries @ Wq + bq. 512 threads: i-dimension split 2-way
// (halves are wave-uniform -> x[i] stays an s_load), LDS combine.
// ---------------------------------------------------------------------------
__global__ __launch_bounds__(512) void qproj(const float* __restrict__ oq,
                                             const float* __restrict__ Wq,
                                             const float* __restrict__ bq,
                                             float* __restrict__ q) {
    __shared__ float sp[2][D];
    const int row = blockIdx.x;        // 0..B*K-1
    const int j   = threadIdx.x & (D - 1);
    const int h   = threadIdx.x >> 8;  // wave-uniform half index
    const float* x = oq + (size_t)row * D;
    const int i0 = h * (D / 2);
    float a0 = 0.f, a1 = 0.f, a2 = 0.f, a3 = 0.f;
#pragma unroll 8
    for (int i = i0; i < i0 + D / 2; i += 4) {
        a0 = fmaf(x[i + 0], Wq[(size_t)(i + 0) * D + j], a0);
        a1 = fmaf(x[i + 1], Wq[(size_t)(i + 1) * D + j], a1);
        a2 = fmaf(x[i + 2], Wq[(size_t)(i + 2) * D + j], a2);
        a3 = fmaf(x[i + 3], Wq[(size_t)(i + 3) * D + j], a3);
    }
    sp[h][j] = (a0 + a1) + (a2 + a3);
    __syncthreads();
    if (h == 0) q[(size_t)row * D + j] = sp[0][j] + sp[1][j] + bq[j];
}

// ---------------------------------------------------------------------------
// Fused big kernel: blocks [0, AB) = attention, blocks [AB, AB+HB) = human.
// ---------------------------------------------------------------------------
__global__ __launch_bounds__(256) void fused_main(const float* __restrict__ feats,
                                                  const float* __restrict__ xyz,
                                                  const float* __restrict__ q,
                                                  const float* __restrict__ hq,
                                                  const float* __restrict__ W1,
                                                  const float* __restrict__ b1,
                                                  const float* __restrict__ W2,
                                                  const float* __restrict__ b2,
                                                  float* __restrict__ part,
                                                  float* __restrict__ out) {
    __shared__ float sxyz[CHN * 3];            // 1.5 KB
    __shared__ float red[4][K * 4];
    __shared__ float sred[2][2][2];

    const int bid = blockIdx.x;
    const int tid = threadIdx.x;

    if (bid >= AB) {
        // ---------------- human contact head: 4 rows per block --------------
        const int hbid = bid - AB;
        const int j    = tid & (HID - 1);
        const int rp   = tid >> 7;
        const int row0 = hbid * 4 + rp * 2;

        const float* x0 = hq + (size_t)row0 * D;
        const float* x1 = x0 + D;
        float acc0 = b1[j];
        float acc1 = acc0;
#pragma unroll 4
        for (int i = 0; i < D; ++i) {
            const float wv = W1[(size_t)i * HID + j];
            acc0 = fmaf(x0[i], wv, acc0);
            acc1 = fmaf(x1[i], wv, acc1);
        }
        const float w2 = W2[j];
        float v0 = fmaxf(acc0, 0.f) * w2;
        float v1 = fmaxf(acc1, 0.f) * w2;
#pragma unroll
        for (int off = 32; off; off >>= 1) {
            v0 += __shfl_xor(v0, off);
            v1 += __shfl_xor(v1, off);
        }
        const int lane = tid & 63;
        const int wh   = (tid >> 6) & 1;
        if (lane == 0) { sred[rp][wh][0] = v0; sred[rp][wh][1] = v1; }
        __syncthreads();
        if (tid < 2) {
            const float bb = b2[0];
            const float l0 = sred[tid][0][0] + sred[tid][1][0] + bb;
            const float l1 = sred[tid][0][1] + sred[tid][1][1] + bb;
            const int r = hbid * 4 + tid * 2;
            out[B * P + r + 0] = l0;
            out[B * P + r + 1] = l1;
            out[r + 0] = 1.f / (1.f + __expf(-l0));
            out[r + 1] = 1.f / (1.f + __expf(-l1));
        }
        return;
    }

    // ------------------------ attention pooling -----------------------------
    const int b    = bid >> 8;                 // batch
    const int ch   = bid & (CH - 1);           // chunk
    const int lane = tid & 63;
    const int w    = tid >> 6;                 // wave 0..3
    const int sg   = lane >> 4;                // subgroup (row slot) 0..3
    const int m    = lane & 15;                // 16-lane index

    const float* fbase = feats + ((size_t)b * N + (size_t)ch * CHN) * D;
    constexpr int NG = CHN / 4;                // 32 row-groups per chunk

    // first prefetch group issued immediately
    f4 f0, f1, f2, f3;
    {
        const float* rp = fbase + (size_t)(w * 4 + sg) * D + m * 4;
        f0 = ntload(rp + 0);
        f1 = ntload(rp + 64);
        f2 = ntload(rp + 128);
        f3 = ntload(rp + 192);
    }

    // stage this chunk's xyz into LDS (coalesced)
    const float* xsrc = xyz + ((size_t)b * N + (size_t)ch * CHN) * 3;
    for (int i = tid; i < CHN * 3; i += 256) sxyz[i] = xsrc[i];

    // q fragments: lane m holds cols {j*64 + 4m .. +4} for j=0..3, per k
    f4 qv[K][4];
#pragma unroll
    for (int k = 0; k < K; ++k)
#pragma unroll
        for (int j = 0; j < 4; ++j)
            qv[k][j] = *(const f4*)(q + (size_t)(b * K + k) * D + j * 64 + m * 4);

    __syncthreads();

    float s_[K] = {0.f, 0.f, 0.f, 0.f};
    float ax[K] = {0.f, 0.f, 0.f, 0.f};
    float ay[K] = {0.f, 0.f, 0.f, 0.f};
    float az[K] = {0.f, 0.f, 0.f, 0.f};

    for (int g = w; g < NG; g += 4) {
        const f4 c0 = f0, c1 = f1, c2 = f2, c3 = f3;
        const int gn = g + 4;
        if (gn < NG) {                          // prefetch next group
            const float* rp = fbase + (size_t)(gn * 4 + sg) * D + m * 4;
            f0 = ntload(rp + 0);
            f1 = ntload(rp + 64);
            f2 = ntload(rp + 128);
            f3 = ntload(rp + 192);
        }
        const int r = g * 4 + sg;

        float d[K];
#pragma unroll
        for (int k = 0; k < K; ++k) {
            float t0 = c0.x * qv[k][0].x;
            t0 = fmaf(c0.y, qv[k][0].y, t0);
            t0 = fmaf(c0.z, qv[k][0].z, t0);
            t0 = fmaf(c0.w, qv[k][0].w, t0);
            float t1 = c1.x * qv[k][1].x;
            t1 = fmaf(c1.y, qv[k][1].y, t1);
            t1 = fmaf(c1.z, qv[k][1].z, t1);
            t1 = fmaf(c1.w, qv[k][1].w, t1);
            t0 = fmaf(c2.x, qv[k][2].x, t0);
            t0 = fmaf(c2.y, qv[k][2].y, t0);
            t0 = fmaf(c2.z, qv[k][2].z, t0);
            t0 = fmaf(c2.w, qv[k][2].w, t0);
            t1 = fmaf(c3.x, qv[k][3].x, t1);
            t1 = fmaf(c3.y, qv[k][3].y, t1);
            t1 = fmaf(c3.z, qv[k][3].z, t1);
            t1 = fmaf(c3.w, qv[k][3].w, t1);
            d[k] = t0 + t1;
        }
#pragma unroll
        for (int k = 0; k < K; ++k) {
            float v = d[k];
            v += __shfl_xor(v, 8);
            v += __shfl_xor(v, 4);
            v += __shfl_xor(v, 2);
            v += __shfl_xor(v, 1);
            d[k] = v;
        }

        const float x = sxyz[r * 3 + 0];
        const float y = sxyz[r * 3 + 1];
        const float z = sxyz[r * 3 + 2];
#pragma unroll
        for (int k = 0; k < K; ++k) {
            const float e = __expf(d[k] * SCL);
            s_[k] += e;
            ax[k] = fmaf(e, x, ax[k]);
            ay[k] = fmaf(e, y, ay[k]);
            az[k] = fmaf(e, z, az[k]);
        }
    }

    // combine the 4 subgroups, then the 4 waves via LDS
#pragma unroll
    for (int k = 0; k < K; ++k) {
        float v;
        v = s_[k]; v += __shfl_xor(v, 16); v += __shfl_xor(v, 32); s_[k] = v;
        v = ax[k]; v += __shfl_xor(v, 16); v += __shfl_xor(v, 32); ax[k] = v;
        v = ay[k]; v += __shfl_xor(v, 16); v += __shfl_xor(v, 32); ay[k] = v;
        v = az[k]; v += __shfl_xor(v, 16); v += __shfl_xor(v, 32); az[k] = v;
    }
    if (lane == 0) {
#pragma unroll
        for (int k = 0; k < K; ++k) {
            red[w][k * 4 + 0] = s_[k];
            red[w][k * 4 + 1] = ax[k];
            red[w][k * 4 + 2] = ay[k];
            red[w][k * 4 + 3] = az[k];
        }
    }
    __syncthreads();
    if (tid < K * 4) {
        const float v = red[0][tid] + red[1][tid] + red[2][tid] + red[3][tid];
        part[((size_t)b * CH + ch) * (K * 4) + tid] = v;
    }
}

// ---------------------------------------------------------------------------
// reduce chunk partials -> object_coords. One block per batch; wave w owns
// query k=w; each lane sums 4 chunk records, then butterfly-reduce.
// ---------------------------------------------------------------------------
__global__ __launch_bounds__(256) void finalize(const float* __restrict__ part,
                                                float* __restrict__ out) {
    const int b = blockIdx.x;                  // 0..B-1
    const int w = threadIdx.x >> 6;            // k
    const int l = threadIdx.x & 63;

    const float* pb = part + (size_t)b * CH * (K * 4) + w * 4;
    f4 v = *(const f4*)(pb + (size_t)l * (K * 4));
#pragma unroll
    for (int r = 1; r < 4; ++r) {
        f4 u = *(const f4*)(pb + (size_t)(l + r * 64) * (K * 4));
        v.x += u.x; v.y += u.y; v.z += u.z; v.w += u.w;
    }
#pragma unroll
    for (int off = 32; off; off >>= 1) {
        v.x += __shfl_xor(v.x, off);
        v.y += __shfl_xor(v.y, off);
        v.z += __shfl_xor(v.z, off);
        v.w += __shfl_xor(v.w, off);
    }
    if (l == 0) {
        const float inv = 1.f / v.x;
        float* o = out + 2 * B * P + (b * K + w) * 3;
        o[0] = v.y * inv;
        o[1] = v.z * inv;
        o[2] = v.w * inv;
    }
}

// ---------------------------------------------------------------------------
extern "C" void kernel_launch(void* const* d_in, const int* in_sizes, int n_in,
                              void* d_out, int out_size, void* d_ws, size_t ws_size,
                              hipStream_t stream) {
    const float* hq    = (const float*)d_in[0];
    const float* oq    = (const float*)d_in[1];
    const float* feats = (const float*)d_in[2];
    const float* xyz   = (const float*)d_in[3];
    const float* W1    = (const float*)d_in[4];
    const float* b1    = (const float*)d_in[5];
    const float* W2    = (const float*)d_in[6];
    const float* b2    = (const float*)d_in[7];
    const float* Wq    = (const float*)d_in[8];
    const float* bq    = (const float*)d_in[9];
    float* out = (float*)d_out;

    float* q    = (float*)d_ws;               // B*K*D floats
    float* part = q + (size_t)B * K * D;      // B*CH*K*4 floats

    qproj<<<B * K, 512, 0, stream>>>(oq, Wq, bq, q);
    fused_main<<<AB + HB, 256, 0, stream>>>(feats, xyz, q, hq, W1, b1, W2, b2,
                                            part, out);
    finalize<<<B, 256, 0, stream>>>(part, out);
}